// Round 2
// baseline (171.688 us; speedup 1.0000x reference)
//
#include <hip/hip_runtime.h>
#include <hip/hip_bf16.h>
#include <math.h>

#define BB 2
#define CC 192
#define LL 32
#define DI 384
#define SS 16
#define RR 12
#define KK 4

// ---------------- K1: one pass over x, all three axis-mean reductions ----------------
// grid = B*C blocks, block = 1024 threads. seq layout: seq[i][b][pos][c]
__global__ void k_reduce(const float* __restrict__ x, float* __restrict__ seq) {
  int bc = blockIdx.x; int b = bc / CC, c = bc % CC;
  const float* base = x + (size_t)bc * 32768;
  int t = threadIdx.x;
  int w = t & 31, r = t >> 5;   // r = d index
  float acc = 0.f;
  __shared__ float sH[32];
  __shared__ float sMat[1024];
  if (t < 32) sH[t] = 0.f;
  __syncthreads();
  for (int h = 0; h < 32; ++h) {
    float v = base[r * 1024 + h * 32 + w];
    acc += v;
    float vv = v;
    #pragma unroll
    for (int off = 32; off > 0; off >>= 1) vv += __shfl_down(vv, off, 64);
    if ((t & 63) == 0) atomicAdd(&sH[h], vv);
  }
  sMat[t] = acc;
  float s0 = acc;
  #pragma unroll
  for (int off = 16; off > 0; off >>= 1) s0 += __shfl_down(s0, off, 32);
  if (w == 0) seq[((0 * BB + b) * 32 + r) * CC + c] = s0 * (1.f / 1024.f);
  __syncthreads();
  if (t < 32) {
    float s2 = 0.f;
    for (int rr = 0; rr < 32; ++rr) s2 += sMat[rr * 32 + t];
    seq[((2 * BB + b) * 32 + t) * CC + c] = s2 * (1.f / 1024.f);
    seq[((1 * BB + b) * 32 + t) * CC + c] = sH[t] * (1.f / 1024.f);
  }
}

// ---------------- K2: LayerNorm + in-proj fused, per token ----------------
// grid = 3*B*32, block = 256
__global__ void k_ln_inproj(const float* __restrict__ seq, const float* __restrict__ ln_w,
                            const float* __restrict__ ln_b, const float* __restrict__ in_w,
                            float* __restrict__ xmz) {
  int tok = blockIdx.x; int i = tok / (BB * 32);
  int t = threadIdx.x;
  __shared__ float srow[CC];
  __shared__ float sw[4], qw[4];
  float v = (t < CC) ? seq[tok * CC + t] : 0.f;
  float s = v, q = v * v;
  #pragma unroll
  for (int off = 32; off > 0; off >>= 1) { s += __shfl_down(s, off, 64); q += __shfl_down(q, off, 64); }
  if ((t & 63) == 0) { sw[t >> 6] = s; qw[t >> 6] = q; }
  __syncthreads();
  float S = sw[0] + sw[1] + sw[2] + sw[3];
  float Q = qw[0] + qw[1] + qw[2] + qw[3];
  float mu = S / CC;
  float var = Q / CC - mu * mu;
  if (t < CC) srow[t] = (v - mu) * rsqrtf(var + 1e-5f) * ln_w[i * CC + t] + ln_b[i * CC + t];
  __syncthreads();
  const float* W = in_w + (size_t)i * 768 * CC;
  const float4* sr = (const float4*)srow;
  for (int j = t; j < 768; j += 256) {
    const float4* wr = (const float4*)(W + j * CC);
    float acc = 0.f;
    #pragma unroll 4
    for (int c4 = 0; c4 < CC / 4; ++c4) {
      float4 a = wr[c4], bq = sr[c4];
      acc += a.x * bq.x + a.y * bq.y + a.z * bq.z + a.w * bq.w;
    }
    xmz[tok * 768 + j] = acc;
  }
}

// ---------------- K3: conv(K=4)+silu + xp-proj + dt-proj+softplus fused, per token ----------------
// grid = 3*B*32, block = 256
__global__ void k_conv_xpdt(const float* __restrict__ xmz, const float* __restrict__ conv_w,
                            const float* __restrict__ conv_b, const float* __restrict__ xp_w,
                            const float* __restrict__ dt_w, const float* __restrict__ dt_b,
                            float* __restrict__ xc, float* __restrict__ dbc, float* __restrict__ dt) {
  int tok = blockIdx.x; int l = tok & 31; int tb = tok >> 5; int i = tb / BB;
  int t = threadIdx.x;
  __shared__ float xr[KK][DI];
  __shared__ float xcl[DI];
  __shared__ float dbcl[44];
  for (int j = t; j < KK * DI; j += 256) {
    int k = j / DI, di = j - k * DI;
    int ls = l + k - 3;
    xr[k][di] = (ls >= 0) ? xmz[(tb * 32 + ls) * 768 + di] : 0.f;
  }
  __syncthreads();
  for (int di = t; di < DI; di += 256) {
    const float* cw = conv_w + (i * DI + di) * KK;
    float acc = conv_b[i * DI + di];
    #pragma unroll
    for (int k = 0; k < KK; ++k) acc += cw[k] * xr[k][di];
    acc = acc / (1.f + expf(-acc));
    xcl[di] = acc;
    xc[tok * DI + di] = acc;
  }
  __syncthreads();
  if (t < 44) {
    const float* wr = xp_w + ((size_t)i * 44 + t) * DI;
    float acc = 0.f;
    for (int c2 = 0; c2 < DI; ++c2) acc += wr[c2] * xcl[c2];
    dbcl[t] = acc;
    dbc[tok * 44 + t] = acc;
  }
  __syncthreads();
  for (int di = t; di < DI; di += 256) {
    const float* wr = dt_w + ((size_t)i * DI + di) * RR;
    float acc = dt_b[i * DI + di];
    #pragma unroll
    for (int r = 0; r < RR; ++r) acc += wr[r] * dbcl[r];
    float sp = (acc > 20.f) ? acc : log1pf(expf(acc));
    dt[tok * DI + di] = sp;
  }
}

// ---------------- K4: selective scan; thread per (i,b,di), 16 states in regs ----------------
// grid = 6 (i*B+b), block = DI
__global__ void k_scan(const float* __restrict__ dbc, const float* __restrict__ dt,
                       const float* __restrict__ xc, const float* __restrict__ xmz,
                       const float* __restrict__ A_log, const float* __restrict__ Dskip,
                       float* __restrict__ y) {
  int ib = blockIdx.x; int i = ib / BB;
  int di = threadIdx.x;
  __shared__ float sB[32][SS], sC[32][SS];
  for (int j = di; j < 32 * SS; j += DI) {
    int l = j >> 4, s = j & 15;
    sB[l][s] = dbc[(ib * 32 + l) * 44 + RR + s];
    sC[l][s] = dbc[(ib * 32 + l) * 44 + RR + SS + s];
  }
  float A[SS];
  #pragma unroll
  for (int s = 0; s < SS; ++s) A[s] = -expf(A_log[((size_t)i * DI + di) * SS + s]);
  float Dsk = Dskip[i * DI + di];
  float h[SS];
  #pragma unroll
  for (int s = 0; s < SS; ++s) h[s] = 0.f;
  __syncthreads();
  for (int l = 0; l < 32; ++l) {
    int tok = ib * 32 + l;
    float dtt = dt[tok * DI + di];
    float xt  = xc[tok * DI + di];
    float z   = xmz[tok * 768 + DI + di];
    float u = dtt * xt;
    float p = 0.f;
    #pragma unroll
    for (int s = 0; s < SS; ++s) {
      float dA = expf(dtt * A[s]);
      h[s] = dA * h[s] + u * sB[l][s];
      p += h[s] * sC[l][s];
    }
    y[tok * DI + di] = (p + Dsk * xt) * (z / (1.f + expf(-z)));
  }
}

// ---------------- K5: out-proj then up-proj, per token ----------------
// grid = 3*B*32, block = 192
__global__ void k_outup(const float* __restrict__ y, const float* __restrict__ out_w,
                        const float* __restrict__ up_w, const float* __restrict__ up_b,
                        float* __restrict__ Z) {
  int tok = blockIdx.x; int tb = tok >> 5; int i = tb / BB;
  __shared__ float yrow[DI];
  __shared__ float mrow[CC];
  int t = threadIdx.x;
  yrow[t] = y[tok * DI + t];
  yrow[t + CC] = y[tok * DI + t + CC];
  __syncthreads();
  const float* wr = out_w + ((size_t)i * CC + t) * DI;
  float acc = 0.f;
  for (int d2 = 0; d2 < DI; ++d2) acc += wr[d2] * yrow[d2];
  mrow[t] = acc;
  __syncthreads();
  const float* ur = up_w + ((size_t)i * CC + t) * CC;
  float z = up_b[i * CC + t];
  for (int c2 = 0; c2 < CC; ++c2) z += ur[c2] * mrow[c2];
  Z[tok * CC + t] = z;
}

// ---------------- K6: gate with inline ctx: ctx -> st -> relu -> Wm -> sigmoid -> Y -> P ----------------
// grid = 3*B*32, block = 192
__global__ void k_gate(const float* __restrict__ Z, const float* __restrict__ Wg_w,
                       const float* __restrict__ Wg_b, const float* __restrict__ Ws_w,
                       const float* __restrict__ Ws_b, const float* __restrict__ Wm_w,
                       const float* __restrict__ Wm_b, const float* __restrict__ po_w,
                       float* __restrict__ P) {
  int blk = blockIdx.x;          // ((g*B+b)*32 + l)
  int gb = blk >> 5;             // g*B+b
  int g = gb / BB, b = gb % BB;
  int o1, o2;
  if (g == 0) { o1 = 1; o2 = 2; } else if (g == 1) { o1 = 0; o2 = 2; } else { o1 = 0; o2 = 1; }
  int t = threadIdx.x;
  __shared__ float gm[2][CC];
  __shared__ float zrow[CC], arow[CC], yrow[CC];
  float s1 = 0.f, s2 = 0.f;
  for (int l = 0; l < 32; ++l) {
    s1 += Z[((o1 * BB + b) * 32 + l) * CC + t];
    s2 += Z[((o2 * BB + b) * 32 + l) * CC + t];
  }
  gm[0][t] = s1 * (1.f / 32.f);
  gm[1][t] = s2 * (1.f / 32.f);
  zrow[t] = Z[blk * CC + t];
  __syncthreads();
  const float* wr = Ws_w + t * CC;
  float st = Ws_b[t];
  for (int c2 = 0; c2 < CC; ++c2) st += wr[c2] * zrow[c2];
  const float* gwr = Wg_w + t * 2 * CC;
  float ctxv = Wg_b[t];
  for (int c2 = 0; c2 < CC; ++c2) ctxv += gwr[c2] * gm[0][c2] + gwr[CC + c2] * gm[1][c2];
  float a = ctxv + st;
  arow[t] = a > 0.f ? a : 0.f;
  __syncthreads();
  const float* mr = Wm_w + t * CC;
  float am = Wm_b[t];
  for (int c2 = 0; c2 < CC; ++c2) am += mr[c2] * arow[c2];
  am = 1.f / (1.f + expf(-am));
  yrow[t] = am * zrow[t];
  __syncthreads();
  const float* pr = po_w + t * (3 * CC) + g * CC;
  float acc = 0.f;
  for (int c2 = 0; c2 < CC; ++c2) acc += pr[c2] * yrow[c2];
  P[blk * CC + t] = acc;
}

// ---------------- K7: final fused: inline instance-norm stats + broadcast + residual ----------------
// grid = B*C, block = 256, float4
__global__ void k_final(const float* __restrict__ x, const float* __restrict__ P,
                        const float* __restrict__ po_b, const float* __restrict__ rs_p,
                        float* __restrict__ out) {
  int bc = blockIdx.x; int b = bc / CC, c = bc % CC;
  __shared__ float p0[32], p1[32], p2[32];
  __shared__ float sbase, ssc;
  int t = threadIdx.x;
  if (t < 32) {
    p0[t] = P[((0 * BB + b) * 32 + t) * CC + c];
    p1[t] = P[((1 * BB + b) * 32 + t) * CC + c];
    p2[t] = P[((2 * BB + b) * 32 + t) * CC + c];
  }
  __syncthreads();
  if (t == 0) {
    float mu = po_b[c];
    float var = 0.f;
    const float* ps[3] = { p0, p1, p2 };
    for (int g = 0; g < 3; ++g) {
      float s = 0.f, q = 0.f;
      for (int l = 0; l < 32; ++l) { float v = ps[g][l]; s += v; q += v * v; }
      float m = s * (1.f / 32.f);
      mu += m;
      var += q * (1.f / 32.f) - m * m;
    }
    float sc = rs_p[0] * rsqrtf(var + 1e-5f);
    ssc = sc;
    sbase = sc * (po_b[c] - mu);
  }
  __syncthreads();
  float sc = ssc;
  if (t < 32) { p0[t] *= sc; p1[t] *= sc; p2[t] *= sc; }
  __syncthreads();
  float basev = sbase;
  const float4* xin = (const float4*)(x + (size_t)bc * 32768);
  float4* xo = (float4*)(out + (size_t)bc * 32768);
  for (int q = t; q < 8192; q += 256) {
    int d = q >> 8, h = (q >> 3) & 31, w4 = (q & 7) * 4;
    float add = basev + p0[d] + p1[h];
    float4 v = xin[q];
    v.x += add + p2[w4];
    v.y += add + p2[w4 + 1];
    v.z += add + p2[w4 + 2];
    v.w += add + p2[w4 + 3];
    xo[q] = v;
  }
}

extern "C" void kernel_launch(void* const* d_in, const int* in_sizes, int n_in,
                              void* d_out, int out_size, void* d_ws, size_t ws_size,
                              hipStream_t stream) {
  const float* x      = (const float*)d_in[0];
  const float* ln_w   = (const float*)d_in[1];
  const float* ln_b   = (const float*)d_in[2];
  const float* in_w   = (const float*)d_in[3];
  const float* conv_w = (const float*)d_in[4];
  const float* conv_b = (const float*)d_in[5];
  const float* xp_w   = (const float*)d_in[6];
  const float* dt_w   = (const float*)d_in[7];
  const float* dt_b   = (const float*)d_in[8];
  const float* A_log  = (const float*)d_in[9];
  const float* Dskip  = (const float*)d_in[10];
  const float* out_w  = (const float*)d_in[11];
  const float* up_w   = (const float*)d_in[12];
  const float* up_b   = (const float*)d_in[13];
  const float* Wg_w   = (const float*)d_in[14];
  const float* Wg_b   = (const float*)d_in[15];
  const float* Ws_w   = (const float*)d_in[16];
  const float* Ws_b   = (const float*)d_in[17];
  const float* Wm_w   = (const float*)d_in[18];
  const float* Wm_b   = (const float*)d_in[19];
  const float* po_w   = (const float*)d_in[20];
  const float* po_b   = (const float*)d_in[21];
  const float* rs_p   = (const float*)d_in[22];
  float* out = (float*)d_out;

  float* ws  = (float*)d_ws;
  float* seq = ws;               // 3*2*32*192 = 36864
  float* xmz = seq + 36864;      // 3*2*32*768 = 147456
  float* xc  = xmz + 147456;     // 73728
  float* dbc = xc  + 73728;      // 8448
  float* dt  = dbc + 8448;       // 73728
  float* y   = dt  + 73728;      // 73728
  float* Z   = y   + 73728;      // 36864
  float* P   = Z   + 36864;      // 36864

  k_reduce<<<dim3(BB * CC), dim3(1024), 0, stream>>>(x, seq);
  k_ln_inproj<<<dim3(3 * BB * 32), dim3(256), 0, stream>>>(seq, ln_w, ln_b, in_w, xmz);
  k_conv_xpdt<<<dim3(3 * BB * 32), dim3(256), 0, stream>>>(xmz, conv_w, conv_b, xp_w, dt_w, dt_b, xc, dbc, dt);
  k_scan<<<dim3(3 * BB), dim3(DI), 0, stream>>>(dbc, dt, xc, xmz, A_log, Dskip, y);
  k_outup<<<dim3(3 * BB * 32), dim3(CC), 0, stream>>>(y, out_w, up_w, up_b, Z);
  k_gate<<<dim3(3 * BB * 32), dim3(CC), 0, stream>>>(Z, Wg_w, Wg_b, Ws_w, Ws_b, Wm_w, Wm_b, po_w, P);
  k_final<<<dim3(BB * CC), dim3(256), 0, stream>>>(x, P, po_b, rs_p, out);
}

// Round 3
// 116.594 us; speedup vs baseline: 1.4725x; 1.4725x over previous
//
#include <hip/hip_runtime.h>
#include <hip/hip_bf16.h>
#include <math.h>

#define BB 2
#define CC 192
#define LL 32
#define DI 384
#define SS 16
#define RR 12
#define KK 4

// ---------------- K1: one pass over x, all three axis-mean reductions ----------------
// grid = B*C blocks, block = 1024. seq layout: seq[i][b][pos][c]
__global__ void k_reduce(const float* __restrict__ x, float* __restrict__ seq) {
  int bc = blockIdx.x; int b = bc / CC, c = bc % CC;
  const float* base = x + (size_t)bc * 32768;
  int t = threadIdx.x;
  int w = t & 31, r = t >> 5;
  float acc = 0.f;
  __shared__ float sH[32];
  __shared__ float sMat[1024];
  if (t < 32) sH[t] = 0.f;
  __syncthreads();
  for (int h = 0; h < 32; ++h) {
    float v = base[r * 1024 + h * 32 + w];
    acc += v;
    float vv = v;
    #pragma unroll
    for (int off = 32; off > 0; off >>= 1) vv += __shfl_down(vv, off, 64);
    if ((t & 63) == 0) atomicAdd(&sH[h], vv);
  }
  sMat[t] = acc;
  float s0 = acc;
  #pragma unroll
  for (int off = 16; off > 0; off >>= 1) s0 += __shfl_down(s0, off, 32);
  if (w == 0) seq[((0 * BB + b) * 32 + r) * CC + c] = s0 * (1.f / 1024.f);
  __syncthreads();
  if (t < 32) {
    float s2 = 0.f;
    for (int rr = 0; rr < 32; ++rr) s2 += sMat[rr * 32 + t];
    seq[((2 * BB + b) * 32 + t) * CC + c] = s2 * (1.f / 1024.f);
    seq[((1 * BB + b) * 32 + t) * CC + c] = sH[t] * (1.f / 1024.f);
  }
}

// ---------------- K2: LayerNorm + in-proj, thread-per-output ----------------
// grid = 3*B*32*4 = 768, block = 192
__global__ void k_ln_inproj(const float* __restrict__ seq, const float* __restrict__ ln_w,
                            const float* __restrict__ ln_b, const float* __restrict__ in_w,
                            float* __restrict__ xmz) {
  int blk = blockIdx.x;
  int tok = blk >> 2, chunk = blk & 3;
  int i = tok >> 6;  // tok / (BB*32)
  int t = threadIdx.x;
  __shared__ float srow[CC];
  __shared__ float sw[3], qw[3];
  float v = seq[tok * CC + t];
  float s = v, q = v * v;
  #pragma unroll
  for (int off = 32; off > 0; off >>= 1) { s += __shfl_down(s, off, 64); q += __shfl_down(q, off, 64); }
  if ((t & 63) == 0) { sw[t >> 6] = s; qw[t >> 6] = q; }
  __syncthreads();
  float S = sw[0] + sw[1] + sw[2], Q = qw[0] + qw[1] + qw[2];
  float mu = S / CC;
  float var = Q / CC - mu * mu;
  srow[t] = (v - mu) * rsqrtf(var + 1e-5f) * ln_w[i * CC + t] + ln_b[i * CC + t];
  __syncthreads();
  int j = chunk * 192 + t;
  const float4* wr = (const float4*)(in_w + (size_t)i * 768 * CC + (size_t)j * CC);
  const float4* sr = (const float4*)srow;
  float acc = 0.f;
  #pragma unroll 8
  for (int c4 = 0; c4 < CC / 4; ++c4) {
    float4 a = wr[c4], bq = sr[c4];
    acc += a.x * bq.x + a.y * bq.y + a.z * bq.z + a.w * bq.w;
  }
  xmz[tok * 768 + j] = acc;
}

// ---------------- K3: conv+silu + xp-proj + dt-proj+softplus, per token ----------------
// grid = 192, block = 384
__global__ void k_conv_xpdt(const float* __restrict__ xmz, const float* __restrict__ conv_w,
                            const float* __restrict__ conv_b, const float* __restrict__ xp_w,
                            const float* __restrict__ dt_w, const float* __restrict__ dt_b,
                            float* __restrict__ xc, float* __restrict__ dbc, float* __restrict__ dt) {
  int tok = blockIdx.x; int l = tok & 31; int tb = tok >> 5; int i = tb / BB;
  int t = threadIdx.x;
  __shared__ float xr[KK][DI];
  __shared__ float xcl[DI];
  __shared__ float dbcl[44];
  #pragma unroll
  for (int j = t; j < KK * DI; j += 384) {
    int k = j / DI, di = j - k * DI;
    int ls = l + k - 3;
    xr[k][di] = (ls >= 0) ? xmz[(tb * 32 + ls) * 768 + di] : 0.f;
  }
  __syncthreads();
  {
    int di = t;
    const float* cw = conv_w + (i * DI + di) * KK;
    float acc = conv_b[i * DI + di];
    #pragma unroll
    for (int k = 0; k < KK; ++k) acc += cw[k] * xr[k][di];
    acc = acc / (1.f + expf(-acc));
    xcl[di] = acc;
    xc[tok * DI + di] = acc;
  }
  __syncthreads();
  if (t < 352) {
    int o = t >> 3, lane = t & 7;
    const float4* wr = (const float4*)(xp_w + ((size_t)i * 44 + o) * DI);
    const float4* xv = (const float4*)xcl;
    float acc = 0.f;
    #pragma unroll
    for (int c4 = lane * 12; c4 < lane * 12 + 12; ++c4) {
      float4 a = wr[c4], bq = xv[c4];
      acc += a.x * bq.x + a.y * bq.y + a.z * bq.z + a.w * bq.w;
    }
    #pragma unroll
    for (int off = 4; off > 0; off >>= 1) acc += __shfl_xor(acc, off, 8);
    if (lane == 0) { dbcl[o] = acc; dbc[tok * 44 + o] = acc; }
  }
  __syncthreads();
  {
    int di = t;
    const float* wr = dt_w + ((size_t)i * DI + di) * RR;
    float acc = dt_b[i * DI + di];
    #pragma unroll
    for (int r = 0; r < RR; ++r) acc += wr[r] * dbcl[r];
    float sp = (acc > 20.f) ? acc : log1pf(expf(acc));
    dt[tok * DI + di] = sp;
  }
}

// ---------------- K4: selective scan; lane per (ib,di,s); LDS-staged inputs ----------------
// grid = 288 (6 ib * 48 di-chunks), block = 128 (8 di-groups x 16 s)
__global__ void k_scan(const float* __restrict__ dbc, const float* __restrict__ dt,
                       const float* __restrict__ xc, const float* __restrict__ xmz,
                       const float* __restrict__ A_log, const float* __restrict__ Dskip,
                       float* __restrict__ y) {
  int ib = blockIdx.x / 48;
  int di0 = (blockIdx.x % 48) * 8;
  int i = ib / BB;
  int t = threadIdx.x;
  int g = t >> 4, s = t & 15;
  int di = di0 + g;
  __shared__ float sdt[32][8], sxc[32][8], sz[32][8];
  __shared__ float sB[32][SS], sC[32][SS];
  #pragma unroll
  for (int j = t; j < 256; j += 128) {
    int l = j >> 3, gg = j & 7;
    int tok = ib * 32 + l;
    sdt[l][gg] = dt[tok * DI + di0 + gg];
    sxc[l][gg] = xc[tok * DI + di0 + gg];
    sz[l][gg]  = xmz[tok * 768 + DI + di0 + gg];
  }
  #pragma unroll
  for (int j = t; j < 512; j += 128) {
    int l = j >> 4, ss = j & 15;
    sB[l][ss] = dbc[(ib * 32 + l) * 44 + RR + ss];
    sC[l][ss] = dbc[(ib * 32 + l) * 44 + RR + SS + ss];
  }
  float A = -expf(A_log[((size_t)i * DI + di) * SS + s]);
  float Dsk = Dskip[i * DI + di];
  float h = 0.f;
  __syncthreads();
  #pragma unroll
  for (int l = 0; l < 32; ++l) {
    float dtt = sdt[l][g];
    float xt  = sxc[l][g];
    float u = dtt * xt;
    h = expf(dtt * A) * h + u * sB[l][s];
    float p = h * sC[l][s];
    #pragma unroll
    for (int off = 8; off > 0; off >>= 1) p += __shfl_xor(p, off, 16);
    if (s == 0) {
      float z = sz[l][g];
      y[(ib * 32 + l) * DI + di] = (p + Dsk * xt) * (z / (1.f + expf(-z)));
    }
  }
}

// ---------------- K5: out-proj then up-proj, split dots, per token ----------------
// grid = 192, block = 384
__global__ void k_outup(const float* __restrict__ y, const float* __restrict__ out_w,
                        const float* __restrict__ up_w, const float* __restrict__ up_b,
                        float* __restrict__ Z) {
  int tok = blockIdx.x; int tb = tok >> 5; int i = tb / BB;
  int t = threadIdx.x;
  __shared__ float yrow[DI];
  __shared__ float mrow[CC];
  __shared__ float part[384];
  yrow[t] = y[tok * DI + t];
  __syncthreads();
  int o = (t < 192) ? t : t - 192;
  int ph = (t < 192) ? 0 : 1;
  {
    const float4* wr = (const float4*)(out_w + ((size_t)i * CC + o) * DI);
    const float4* yv = (const float4*)yrow;
    float acc = 0.f;
    #pragma unroll 8
    for (int c4 = ph * 48; c4 < ph * 48 + 48; ++c4) {
      float4 a = wr[c4], bq = yv[c4];
      acc += a.x * bq.x + a.y * bq.y + a.z * bq.z + a.w * bq.w;
    }
    part[t] = acc;
  }
  __syncthreads();
  if (t < 192) mrow[t] = part[t] + part[t + 192];
  __syncthreads();
  {
    const float4* ur = (const float4*)(up_w + ((size_t)i * CC + o) * CC);
    const float4* mv = (const float4*)mrow;
    float acc = 0.f;
    #pragma unroll 8
    for (int c4 = ph * 24; c4 < ph * 24 + 24; ++c4) {
      float4 a = ur[c4], bq = mv[c4];
      acc += a.x * bq.x + a.y * bq.y + a.z * bq.z + a.w * bq.w;
    }
    part[t] = acc;
  }
  __syncthreads();
  if (t < 192) Z[tok * CC + t] = up_b[i * CC + t] + part[t] + part[t + 192];
}

// ---------------- K6: gate with inline ctx, split dots ----------------
// grid = 192, block = 384
__global__ void k_gate(const float* __restrict__ Z, const float* __restrict__ Wg_w,
                       const float* __restrict__ Wg_b, const float* __restrict__ Ws_w,
                       const float* __restrict__ Ws_b, const float* __restrict__ Wm_w,
                       const float* __restrict__ Wm_b, const float* __restrict__ po_w,
                       float* __restrict__ P) {
  int blk = blockIdx.x;          // ((g*B+b)*32 + l)
  int gb = blk >> 5;
  int g = gb / BB, b = gb % BB;
  int o1, o2;
  if (g == 0) { o1 = 1; o2 = 2; } else if (g == 1) { o1 = 0; o2 = 2; } else { o1 = 0; o2 = 1; }
  int t = threadIdx.x;
  __shared__ float gm0[CC], gm1[CC], zrow[CC], arow[CC], yrow[CC];
  __shared__ float pa[384], pb[384];
  if (t < 192) {
    float s1 = 0.f;
    for (int l = 0; l < 32; ++l) s1 += Z[((o1 * BB + b) * 32 + l) * CC + t];
    gm0[t] = s1 * (1.f / 32.f);
    zrow[t] = Z[blk * CC + t];
  } else {
    int tt = t - 192;
    float s2 = 0.f;
    for (int l = 0; l < 32; ++l) s2 += Z[((o2 * BB + b) * 32 + l) * CC + tt];
    gm1[tt] = s2 * (1.f / 32.f);
  }
  __syncthreads();
  int o = (t < 192) ? t : t - 192;
  int ph = (t < 192) ? 0 : 1;
  {
    const float4* wr = (const float4*)(Ws_w + (size_t)o * CC);
    const float4* zv = (const float4*)zrow;
    float acc = 0.f;
    #pragma unroll 8
    for (int c4 = ph * 24; c4 < ph * 24 + 24; ++c4) {
      float4 a = wr[c4], bq = zv[c4];
      acc += a.x * bq.x + a.y * bq.y + a.z * bq.z + a.w * bq.w;
    }
    pa[t] = acc;
    const float4* gwr = (const float4*)(Wg_w + (size_t)o * 2 * CC + ph * CC);
    const float4* gmv = (const float4*)(ph == 0 ? gm0 : gm1);
    float acc2 = 0.f;
    #pragma unroll 8
    for (int c4 = 0; c4 < 48; ++c4) {
      float4 a = gwr[c4], bq = gmv[c4];
      acc2 += a.x * bq.x + a.y * bq.y + a.z * bq.z + a.w * bq.w;
    }
    pb[t] = acc2;
  }
  __syncthreads();
  if (t < 192) {
    float st = Ws_b[t] + pa[t] + pa[t + 192];
    float ctxv = Wg_b[t] + pb[t] + pb[t + 192];
    float a = ctxv + st;
    arow[t] = a > 0.f ? a : 0.f;
  }
  __syncthreads();
  {
    const float4* mr = (const float4*)(Wm_w + (size_t)o * CC);
    const float4* av = (const float4*)arow;
    float acc = 0.f;
    #pragma unroll 8
    for (int c4 = ph * 24; c4 < ph * 24 + 24; ++c4) {
      float4 a = mr[c4], bq = av[c4];
      acc += a.x * bq.x + a.y * bq.y + a.z * bq.z + a.w * bq.w;
    }
    pa[t] = acc;
  }
  __syncthreads();
  if (t < 192) {
    float am = Wm_b[t] + pa[t] + pa[t + 192];
    am = 1.f / (1.f + expf(-am));
    yrow[t] = am * zrow[t];
  }
  __syncthreads();
  {
    const float4* pr = (const float4*)(po_w + (size_t)o * (3 * CC) + g * CC);
    const float4* yv = (const float4*)yrow;
    float acc = 0.f;
    #pragma unroll 8
    for (int c4 = ph * 24; c4 < ph * 24 + 24; ++c4) {
      float4 a = pr[c4], bq = yv[c4];
      acc += a.x * bq.x + a.y * bq.y + a.z * bq.z + a.w * bq.w;
    }
    pb[t] = acc;
  }
  __syncthreads();
  if (t < 192) P[blk * CC + t] = pb[t] + pb[t + 192];
}

// ---------------- K7: final fused: warp-parallel stats + broadcast + residual ----------------
// grid = B*C*2, block = 256
__global__ void k_final(const float* __restrict__ x, const float* __restrict__ P,
                        const float* __restrict__ po_b, const float* __restrict__ rs_p,
                        float* __restrict__ out) {
  int bc = blockIdx.x >> 1; int half = blockIdx.x & 1;
  int b = bc / CC, c = bc % CC;
  __shared__ float p0[32], p1[32], p2[32];
  __shared__ float sbase;
  int t = threadIdx.x;
  if (t < 32) {
    float v0 = P[((0 * BB + b) * 32 + t) * CC + c];
    float v1 = P[((1 * BB + b) * 32 + t) * CC + c];
    float v2 = P[((2 * BB + b) * 32 + t) * CC + c];
    float s0 = v0, q0 = v0 * v0, s1 = v1, q1 = v1 * v1, s2 = v2, q2 = v2 * v2;
    #pragma unroll
    for (int off = 16; off > 0; off >>= 1) {
      s0 += __shfl_xor(s0, off, 32); q0 += __shfl_xor(q0, off, 32);
      s1 += __shfl_xor(s1, off, 32); q1 += __shfl_xor(q1, off, 32);
      s2 += __shfl_xor(s2, off, 32); q2 += __shfl_xor(q2, off, 32);
    }
    float m0 = s0 * (1.f / 32.f), m1 = s1 * (1.f / 32.f), m2 = s2 * (1.f / 32.f);
    float var = (q0 * (1.f / 32.f) - m0 * m0) + (q1 * (1.f / 32.f) - m1 * m1) + (q2 * (1.f / 32.f) - m2 * m2);
    float mu = po_b[c] + m0 + m1 + m2;
    float sc = rs_p[0] * rsqrtf(var + 1e-5f);
    p0[t] = v0 * sc; p1[t] = v1 * sc; p2[t] = v2 * sc;
    if (t == 0) sbase = sc * (po_b[c] - mu);
  }
  __syncthreads();
  float basev = sbase;
  const float4* xin = (const float4*)(x + (size_t)bc * 32768);
  float4* xo = (float4*)(out + (size_t)bc * 32768);
  int q0i = half * 4096;
  #pragma unroll 4
  for (int q = q0i + t; q < q0i + 4096; q += 256) {
    int d = q >> 8, h = (q >> 3) & 31, w4 = (q & 7) * 4;
    float add = basev + p0[d] + p1[h];
    float4 v = xin[q];
    v.x += add + p2[w4];
    v.y += add + p2[w4 + 1];
    v.z += add + p2[w4 + 2];
    v.w += add + p2[w4 + 3];
    xo[q] = v;
  }
}

extern "C" void kernel_launch(void* const* d_in, const int* in_sizes, int n_in,
                              void* d_out, int out_size, void* d_ws, size_t ws_size,
                              hipStream_t stream) {
  const float* x      = (const float*)d_in[0];
  const float* ln_w   = (const float*)d_in[1];
  const float* ln_b   = (const float*)d_in[2];
  const float* in_w   = (const float*)d_in[3];
  const float* conv_w = (const float*)d_in[4];
  const float* conv_b = (const float*)d_in[5];
  const float* xp_w   = (const float*)d_in[6];
  const float* dt_w   = (const float*)d_in[7];
  const float* dt_b   = (const float*)d_in[8];
  const float* A_log  = (const float*)d_in[9];
  const float* Dskip  = (const float*)d_in[10];
  const float* out_w  = (const float*)d_in[11];
  const float* up_w   = (const float*)d_in[12];
  const float* up_b   = (const float*)d_in[13];
  const float* Wg_w   = (const float*)d_in[14];
  const float* Wg_b   = (const float*)d_in[15];
  const float* Ws_w   = (const float*)d_in[16];
  const float* Ws_b   = (const float*)d_in[17];
  const float* Wm_w   = (const float*)d_in[18];
  const float* Wm_b   = (const float*)d_in[19];
  const float* po_w   = (const float*)d_in[20];
  const float* po_b   = (const float*)d_in[21];
  const float* rs_p   = (const float*)d_in[22];
  float* out = (float*)d_out;

  float* ws  = (float*)d_ws;
  float* seq = ws;               // 36864
  float* xmz = seq + 36864;      // 147456
  float* xc  = xmz + 147456;     // 73728
  float* dbc = xc  + 73728;      // 8448
  float* dt  = dbc + 8448;       // 73728
  float* y   = dt  + 73728;      // 73728
  float* Z   = y   + 73728;      // 36864
  float* P   = Z   + 36864;      // 36864

  k_reduce<<<dim3(BB * CC), dim3(1024), 0, stream>>>(x, seq);
  k_ln_inproj<<<dim3(768), dim3(192), 0, stream>>>(seq, ln_w, ln_b, in_w, xmz);
  k_conv_xpdt<<<dim3(192), dim3(384), 0, stream>>>(xmz, conv_w, conv_b, xp_w, dt_w, dt_b, xc, dbc, dt);
  k_scan<<<dim3(288), dim3(128), 0, stream>>>(dbc, dt, xc, xmz, A_log, Dskip, y);
  k_outup<<<dim3(192), dim3(384), 0, stream>>>(y, out_w, up_w, up_b, Z);
  k_gate<<<dim3(192), dim3(384), 0, stream>>>(Z, Wg_w, Wg_b, Ws_w, Ws_b, Wm_w, Wm_b, po_w, P);
  k_final<<<dim3(BB * CC * 2), dim3(256), 0, stream>>>(x, P, po_b, rs_p, out);
}